// Round 4
// baseline (60.669 us; speedup 1.0000x reference)
//
#include <hip/hip_runtime.h>
#include <math.h>

// ASD between two 16384x3 fp32 point sets.
//
// R1: LDS-pipe-bound at QPT=2 -> QPT=8 broadcast amortization (71->46 us).
// R2->R3: occupancy 2->4 waves/SIMD: 46->43.4 us only. Conclusion: VALU
//   issue-rate-bound at ~3 cyc/VOP3 (matches m07 = 66% of 157 TF ceiling).
// R4: cut instructions/pair 4.0 -> 2.5 via packed fp32 (v_pk_fma_f32,
//   CDNA gfx90a+): pack TWO refs per VOP3P op, queries duplicated into
//   float2 coefficient registers. __builtin_elementwise_fma on float2
//   selects llvm.fma.v2f32 -> v_pk_fma_f32 (scalarizes harmlessly if not).
//   Model: VALU ~22 us, LDS broadcast pipe ~19 us -> balanced.

typedef float v2f __attribute__((ext_vector_type(2)));

#define NPTS    16384
#define THREADS 256
#define QPT     8                    // queries per thread
#define QBLK    (THREADS * QPT)      // 2048 queries per block
#define NQB     (NPTS / QBLK)        // 8 query-blocks per direction
#define NCHUNK  64
#define CHUNK   (NPTS / NCHUNK)      // 256 refs per chunk
#define CPAIRS  (CHUNK / 2)          // 128 ref pairs

__global__ __launch_bounds__(THREADS, 4) void asd_min_kernel(
    const float* __restrict__ real_pts,
    const float* __restrict__ pred_pts,
    unsigned int* __restrict__ ws)
{
    const int bid   = blockIdx.x;          // 1024 blocks: 2 dirs x 8 qb x 64 chunks
    const int dir   = bid >> 9;
    const int rem   = bid & 511;
    const int chunk = rem >> 3;            // 0..63
    const int qb    = rem & 7;             // 0..7

    // dir 0: pred -> real ; dir 1: real -> pred
    const float* __restrict__ qpts = dir ? real_pts : pred_pts;
    const float* __restrict__ rpts = dir ? pred_pts : real_pts;

    // Ref pair j: sref[2j] = (x0,x1,y0,y1), sref[2j+1] = (z0,z1,r2_0,r2_1).
    // ds_read_b128 quads split into even-aligned VGPR pairs for VOP3P for free.
    __shared__ float4 sref[CHUNK];         // 4 KB

    const int tid = threadIdx.x;

    const int rbase = chunk * CHUNK;
    for (int j = tid; j < CPAIRS; j += THREADS) {
        const int r0 = rbase + 2 * j;
        const float x0 = rpts[r0 * 3 + 0], y0 = rpts[r0 * 3 + 1], z0 = rpts[r0 * 3 + 2];
        const float x1 = rpts[r0 * 3 + 3], y1 = rpts[r0 * 3 + 4], z1 = rpts[r0 * 3 + 5];
        sref[2 * j + 0] = make_float4(x0, x1, y0, y1);
        sref[2 * j + 1] = make_float4(z0, z1,
                                      fmaf(x0, x0, fmaf(y0, y0, z0 * z0)),
                                      fmaf(x1, x1, fmaf(y1, y1, z1 * z1)));
    }

    // Query coefficients, pre-scaled by -2 and duplicated into both halves.
    v2f qx2[QPT], qy2[QPT], qz2[QPT], mp[QPT];
    float q2[QPT];
    const int q0 = qb * QBLK + tid;
#pragma unroll
    for (int k = 0; k < QPT; ++k) {
        const int qi = q0 + k * THREADS;
        const float x = qpts[qi * 3 + 0];
        const float y = qpts[qi * 3 + 1];
        const float z = qpts[qi * 3 + 2];
        qx2[k] = (v2f){-2.0f * x, -2.0f * x};
        qy2[k] = (v2f){-2.0f * y, -2.0f * y};
        qz2[k] = (v2f){-2.0f * z, -2.0f * z};
        q2[k]  = fmaf(x, x, fmaf(y, y, z * z));
        mp[k]  = (v2f){INFINITY, INFINITY};   // packed running min of (r2 - 2 q.r)
    }

    __syncthreads();

#pragma unroll 4
    for (int j = 0; j < CPAIRS; ++j) {
        const float4 a = sref[2 * j + 0];     // broadcast reads, conflict-free
        const float4 b = sref[2 * j + 1];
        const v2f rx = (v2f){a.x, a.y};
        const v2f ry = (v2f){a.z, a.w};
        const v2f rz = (v2f){b.x, b.y};
        const v2f r2 = (v2f){b.z, b.w};
#pragma unroll
        for (int k = 0; k < QPT; ++k) {
            v2f t = __builtin_elementwise_fma(qx2[k], rx, r2);
            t = __builtin_elementwise_fma(qy2[k], ry, t);
            t = __builtin_elementwise_fma(qz2[k], rz, t);
            mp[k] = __builtin_elementwise_min(mp[k], t);   // 2x v_min_f32
        }
    }

#pragma unroll
    for (int k = 0; k < QPT; ++k) {
        const int qi = q0 + k * THREADS;
        const float m  = fminf(mp[k][0], mp[k][1]);
        const float d2 = fmaxf(m + q2[k], 0.0f);   // clamp (matches ref; keeps
                                                   // uint-order isomorphism)
        atomicMin(&ws[dir * NPTS + qi], __float_as_uint(d2));
    }
}

__global__ __launch_bounds__(1024) void asd_reduce_kernel(
    const unsigned int* __restrict__ ws, float* __restrict__ out)
{
    const int tid = threadIdx.x;
    float s = 0.0f;

    for (int q = tid; q < 2 * NPTS; q += 1024)
        s += sqrtf(__uint_as_float(ws[q]));

    __shared__ float red[16];
#pragma unroll
    for (int off = 32; off > 0; off >>= 1)
        s += __shfl_down(s, off, 64);
    const int wave = tid >> 6;
    const int lane = tid & 63;
    if (lane == 0) red[wave] = s;
    __syncthreads();
    if (tid < 16) {
        float v = red[tid];
#pragma unroll
        for (int off = 8; off > 0; off >>= 1)
            v += __shfl_down(v, off, 16);
        if (tid == 0) out[0] = v / (float)(2 * NPTS);
    }
}

extern "C" void kernel_launch(void* const* d_in, const int* in_sizes, int n_in,
                              void* d_out, int out_size, void* d_ws, size_t ws_size,
                              hipStream_t stream)
{
    const float* real_pts = (const float*)d_in[0];
    const float* pred_pts = (const float*)d_in[1];
    float* out = (float*)d_out;
    unsigned int* ws = (unsigned int*)d_ws;    // 2*16384 uints = 128 KiB

    // Init per-query running mins to a huge float (0x7F7F7F7F = 3.39e38).
    hipMemsetAsync(ws, 0x7F, 2 * NPTS * sizeof(unsigned int), stream);

    asd_min_kernel<<<2 * NQB * NCHUNK, THREADS, 0, stream>>>(real_pts, pred_pts, ws);
    asd_reduce_kernel<<<1, 1024, 0, stream>>>(ws, out);
}

// Round 5
// 42.849 us; speedup vs baseline: 1.4159x; 1.4159x over previous
//
#include <hip/hip_runtime.h>
#include <math.h>

// ASD between two 16384x3 fp32 point sets, uniform in [0,128)^3.
//
// R1-R4 (brute force O(N^2)): 96 -> 58.7 us; main kernel pinned at ~45 us
// against the fp32 VALU issue roofline (~27 us math floor, v_pk_fma_f32
// is half-rate on gfx950 so packing gained nothing). Remaining levers < 1.3x.
//
// R5: uniform-grid spatial binning. 16^3 cells of 8.0 units, ~4 pts/cell.
// Counting-sort both sets, then each query scans the 3^3 neighborhood
// (~108 candidates instead of 16384: 150x work cut). Rigorous stop rule:
// after scanning Chebyshev radius k, any point outside is > 8k away, so
// stop when best_d2 <= (8k)^2; else expand (P ~ 6e-8 per query, loop kept
// for correctness; k<=16 covers the whole grid).
//
// Determinism: scatter order within a cell is atomic-order-dependent, but
// min over a cell's point SET is order-independent; all sums are fixed-order
// trees (no float atomics). Same input -> bit-identical output.
//
// NN kernel: 8 lanes per query; lanes stride a cell's points (consecutive
// float4 -> coalesced 128B per group), 3x shfl_xor min-reduce.

#define NPTS     16384
#define G        16
#define NC       (G * G * G)       // 4096 cells
#define CELL     8.0f
#define INV_CELL 0.125f

// ws layout (u32 index):            bytes
//  hist [2][NC]          @ 0        32768
//  off  [2][NC+1]        @ 8192     32776
//  cur  [2][NC]          @ 16896    32768
//  srt  [2][NPTS] float4 @ 25088    524288   (byte 100352, 16B aligned)
//  bsum [1024]  float    @ 156160   4096     -> total 755712 B < 1 MiB
#define W_HIST 0
#define W_OFF  8192
#define W_CUR  16896
#define W_SRT  25088
#define W_BSUM 156160

__device__ __forceinline__ int clampi(int v, int lo, int hi) {
    return v < lo ? lo : (v > hi ? hi : v);
}

__device__ __forceinline__ int cell_of(float x, float y, float z) {
    const int cx = clampi((int)(x * INV_CELL), 0, G - 1);
    const int cy = clampi((int)(y * INV_CELL), 0, G - 1);
    const int cz = clampi((int)(z * INV_CELL), 0, G - 1);
    return (cz * G + cy) * G + cx;
}

__global__ __launch_bounds__(256) void hist_kernel(
    const float* __restrict__ real, const float* __restrict__ pred,
    unsigned* __restrict__ hist)
{
    const int g   = blockIdx.x * 256 + threadIdx.x;   // 0..32767
    const int set = g >> 14;
    const int i   = g & (NPTS - 1);
    const float* __restrict__ p = set ? pred : real;  // set0=real, set1=pred
    const float x = p[3 * i], y = p[3 * i + 1], z = p[3 * i + 2];
    atomicAdd(&hist[set * NC + cell_of(x, y, z)], 1u);
}

// Dual exclusive scan of hist[0][0..NC) and hist[1][0..NC) in one block.
__global__ __launch_bounds__(1024) void scan_kernel(
    const unsigned* __restrict__ hist,
    unsigned* __restrict__ off, unsigned* __restrict__ cur)
{
    const int tid  = threadIdx.x;
    const int lane = tid & 63;
    const int wave = tid >> 6;
    const int base = tid * 4;                          // 4 elements per thread

    unsigned a0[4], a1[4], s0 = 0, s1 = 0;
#pragma unroll
    for (int j = 0; j < 4; ++j) {
        a0[j] = hist[base + j];        s0 += a0[j];
        a1[j] = hist[NC + base + j];   s1 += a1[j];
    }

    // Inclusive wave scan of per-thread sums.
    unsigned i0 = s0, i1 = s1;
#pragma unroll
    for (int d = 1; d < 64; d <<= 1) {
        const unsigned t0 = __shfl_up(i0, d, 64);
        const unsigned t1 = __shfl_up(i1, d, 64);
        if (lane >= d) { i0 += t0; i1 += t1; }
    }

    __shared__ unsigned w0[16], w1[16];
    if (lane == 63) { w0[wave] = i0; w1[wave] = i1; }
    __syncthreads();
    if (tid == 0) {                                    // scan 16 wave totals
        unsigned r0 = 0, r1 = 0;
        for (int w = 0; w < 16; ++w) {
            const unsigned t0 = w0[w]; w0[w] = r0; r0 += t0;
            const unsigned t1 = w1[w]; w1[w] = r1; r1 += t1;
        }
    }
    __syncthreads();

    unsigned e0 = w0[wave] + (i0 - s0);                // thread-exclusive prefix
    unsigned e1 = w1[wave] + (i1 - s1);
#pragma unroll
    for (int j = 0; j < 4; ++j) {
        off[base + j]            = e0;
        cur[base + j]            = e0;
        off[(NC + 1) + base + j] = e1;
        cur[NC + base + j]       = e1;
        e0 += a0[j];
        e1 += a1[j];
    }
    if (tid == 0) { off[NC] = NPTS; off[(NC + 1) + NC] = NPTS; }
}

__global__ __launch_bounds__(256) void scatter_kernel(
    const float* __restrict__ real, const float* __restrict__ pred,
    unsigned* __restrict__ cur, float4* __restrict__ srt)
{
    const int g   = blockIdx.x * 256 + threadIdx.x;
    const int set = g >> 14;
    const int i   = g & (NPTS - 1);
    const float* __restrict__ p = set ? pred : real;
    const float x = p[3 * i], y = p[3 * i + 1], z = p[3 * i + 2];
    const unsigned pos = atomicAdd(&cur[set * NC + cell_of(x, y, z)], 1u);
    srt[set * NPTS + pos] = make_float4(x, y, z, 0.0f);
}

// 8 lanes per query. dir0 (g<16384): query=pred[g], refs=sorted real (set0).
// dir1: query=real[g-16384], refs=sorted pred (set1).
__global__ __launch_bounds__(256) void nn_kernel(
    const float* __restrict__ real, const float* __restrict__ pred,
    const unsigned* __restrict__ off, const float4* __restrict__ srt,
    float* __restrict__ bsum)
{
    const int tid   = threadIdx.x;
    const int lane8 = tid & 7;
    const int g     = blockIdx.x * 32 + (tid >> 3);   // 0..32767
    const int dir   = g >> 14;
    const int qi    = g & (NPTS - 1);

    const float* __restrict__ qp    = dir ? real : pred;
    const unsigned* __restrict__ offr = off + dir * (NC + 1);
    const float4* __restrict__ refs   = srt + dir * NPTS;

    const float qx = qp[3 * qi], qy = qp[3 * qi + 1], qz = qp[3 * qi + 2];
    const int qcx = clampi((int)(qx * INV_CELL), 0, G - 1);
    const int qcy = clampi((int)(qy * INV_CELL), 0, G - 1);
    const int qcz = clampi((int)(qz * INV_CELL), 0, G - 1);

    float best = INFINITY;
    int k = 1;
    for (;;) {
        float b = INFINITY;
        const int z0 = clampi(qcz - k, 0, G - 1), z1 = clampi(qcz + k, 0, G - 1);
        const int y0 = clampi(qcy - k, 0, G - 1), y1 = clampi(qcy + k, 0, G - 1);
        const int x0 = clampi(qcx - k, 0, G - 1), x1 = clampi(qcx + k, 0, G - 1);
        for (int cz = z0; cz <= z1; ++cz) {
            for (int cy = y0; cy <= y1; ++cy) {
                const int rowc = (cz * G + cy) * G;
                for (int cx = x0; cx <= x1; ++cx) {
                    const int c = rowc + cx;
                    const unsigned s = offr[c];
                    const unsigned e = offr[c + 1];
                    for (unsigned i = s + lane8; i < e; i += 8) {
                        const float4 r = refs[i];
                        const float dx = qx - r.x;
                        const float dy = qy - r.y;
                        const float dz = qz - r.z;
                        b = fminf(b, fmaf(dx, dx, fmaf(dy, dy, dz * dz)));
                    }
                }
            }
        }
        // 8-lane group min (bits 0..2 stay inside the group).
        b = fminf(b, __shfl_xor(b, 1, 64));
        b = fminf(b, __shfl_xor(b, 2, 64));
        b = fminf(b, __shfl_xor(b, 4, 64));
        best = fminf(best, b);
        const float reach = CELL * (float)k;
        if (best <= reach * reach || k >= G) break;   // outside pts are > 8k away
        ++k;                                          // expand (P ~ 6e-8/query)
    }

    // Deterministic per-block partial sum of sqrt(best) over 32 groups.
    __shared__ float gs[32];
    if (lane8 == 0) gs[tid >> 3] = sqrtf(best);
    __syncthreads();
    if (tid == 0) {
        float s = 0.0f;
        for (int j = 0; j < 32; ++j) s += gs[j];
        bsum[blockIdx.x] = s;
    }
}

__global__ __launch_bounds__(1024) void sum_kernel(
    const float* __restrict__ bsum, float* __restrict__ out)
{
    const int tid = threadIdx.x;
    float s = bsum[tid];                              // exactly 1024 partials
#pragma unroll
    for (int o = 32; o > 0; o >>= 1)
        s += __shfl_down(s, o, 64);
    __shared__ float red[16];
    const int wave = tid >> 6, lane = tid & 63;
    if (lane == 0) red[wave] = s;
    __syncthreads();
    if (tid < 16) {
        float v = red[tid];
#pragma unroll
        for (int o = 8; o > 0; o >>= 1)
            v += __shfl_down(v, o, 16);
        if (tid == 0) out[0] = v * (1.0f / (float)(2 * NPTS));
    }
}

extern "C" void kernel_launch(void* const* d_in, const int* in_sizes, int n_in,
                              void* d_out, int out_size, void* d_ws, size_t ws_size,
                              hipStream_t stream)
{
    const float* real_pts = (const float*)d_in[0];
    const float* pred_pts = (const float*)d_in[1];
    float* out = (float*)d_out;
    unsigned* W = (unsigned*)d_ws;

    unsigned* hist = W + W_HIST;
    unsigned* off  = W + W_OFF;
    unsigned* cur  = W + W_CUR;
    float4*   srt  = (float4*)(W + W_SRT);
    float*    bsum = (float*)(W + W_BSUM);

    hipMemsetAsync(hist, 0, 2 * NC * sizeof(unsigned), stream);
    hist_kernel   <<<2 * NPTS / 256, 256, 0, stream>>>(real_pts, pred_pts, hist);
    scan_kernel   <<<1, 1024, 0, stream>>>(hist, off, cur);
    scatter_kernel<<<2 * NPTS / 256, 256, 0, stream>>>(real_pts, pred_pts, cur, srt);
    nn_kernel     <<<2 * NPTS / 32, 256, 0, stream>>>(real_pts, pred_pts, off, srt, bsum);
    sum_kernel    <<<1, 1024, 0, stream>>>(bsum, out);
}